// Round 15
// baseline (490.588 us; speedup 1.0000x reference)
//
#include <hip/hip_runtime.h>
#include <hip/hip_fp16.h>
#include <math.h>

typedef _Float16 half8  __attribute__((ext_vector_type(8)));
typedef _Float16 half4v __attribute__((ext_vector_type(4)));
typedef float    floatx4 __attribute__((ext_vector_type(4)));

#define NB   4
#define LL   8192
#define FF   1024
#define HH   16
#define DD   64
#define MTOT 32768
#define KK   1024
#define NN   1024
#define ZSCALE 65536.0f

__device__ __forceinline__ void gload_lds16(const void* g, void* l) {
  __builtin_amdgcn_global_load_lds(
      (const __attribute__((address_space(1))) void*)g,
      (__attribute__((address_space(3))) void*)l, 16, 0, 0);
}

__device__ __forceinline__ float phi_act(float x) {
  return x > 0.f ? x + 1.f : __expf(x);
}

// ---------- fused elementwise f32 -> f16 for two arrays ----------
__global__ void k_cvt2(const float* __restrict__ a, const float* __restrict__ b,
                       _Float16* __restrict__ da, _Float16* __restrict__ db, int n4each) {
  int stride = gridDim.x * blockDim.x;
  for (int i = blockIdx.x * blockDim.x + threadIdx.x; i < 2 * n4each; i += stride) {
    const float* s; _Float16* d; int j;
    if (i < n4each) { s = a; d = da; j = i; }
    else            { s = b; d = db; j = i - n4each; }
    float4 v = reinterpret_cast<const float4*>(s)[j];
    half4v h;
    h[0] = (_Float16)v.x; h[1] = (_Float16)v.y; h[2] = (_Float16)v.z; h[3] = (_Float16)v.w;
    reinterpret_cast<half4v*>(d)[j] = h;
  }
}

// ---------- elementwise f32 -> f16 ----------
__global__ void k_cvt(const float* __restrict__ src, _Float16* __restrict__ dst, int n4) {
  int stride = gridDim.x * blockDim.x;
  for (int i = blockIdx.x * blockDim.x + threadIdx.x; i < n4; i += stride) {
    float4 v = reinterpret_cast<const float4*>(src)[i];
    half4v h;
    h[0] = (_Float16)v.x; h[1] = (_Float16)v.y; h[2] = (_Float16)v.z; h[3] = (_Float16)v.w;
    reinterpret_cast<half4v*>(dst)[i] = h;
  }
}

// ---------- transpose+convert weights ----------
// Wq -> T0 [1024][1024]; Wk,Wv -> TKV [2048][1024] interleaved per head:
//   head h rows h*128..h*128+63 = WkT(h), rows h*128+64..+127 = WvT(h).
__global__ void k_cvt_t(const float* __restrict__ W0, const float* __restrict__ W1,
                        const float* __restrict__ W2,
                        _Float16* __restrict__ T0, _Float16* __restrict__ TKV) {
  __shared__ float tile[32][33];
  int bid = blockIdx.x;
  int w = bid >> 10, rem = bid & 1023;
  int ti = rem >> 5, tj = rem & 31;
  const float* src = (w == 0) ? W0 : (w == 1) ? W1 : W2;
  int t = threadIdx.x;
  int r = t >> 3, c4 = (t & 7) << 2;
  float4 v = *reinterpret_cast<const float4*>(&src[(size_t)(ti * 32 + r) * FF + tj * 32 + c4]);
  tile[r][c4 + 0] = v.x; tile[r][c4 + 1] = v.y; tile[r][c4 + 2] = v.z; tile[r][c4 + 3] = v.w;
  __syncthreads();
  half4v h;
  h[0] = (_Float16)tile[c4 + 0][r];
  h[1] = (_Float16)tile[c4 + 1][r];
  h[2] = (_Float16)tile[c4 + 2][r];
  h[3] = (_Float16)tile[c4 + 3][r];
  int n = tj * 32 + r;
  _Float16* dst; size_t orow;
  if (w == 0) { dst = T0;  orow = n; }
  else        { dst = TKV; orow = (size_t)(n >> 6) * 128 + (n & 63) + (w == 2 ? 64 : 0); }
  *reinterpret_cast<half4v*>(&dst[orow * FF + ti * 32 + c4]) = h;
}

// ============ 128x128-tile quadrant-schedule GEMM (BK=64, 4 waves 2x2) ============
// r15: tile halved 256->128, LDS 128KB->64KB => 2 blocks/CU (was 1).  Theory:
// m114/m97 inter-block overlap hides barrier drains that the 1-block/CU 256²
// config exposes.  Schedule/swizzle/vmcnt identical (same stage_half count per
// K-tile, same vmcnt(4) at ph3).  MODE1 tile = one [K(h)|V(h)] head pair.
// LDS planes 8KB: [2 buf][A-h0, A-h1, B-h0, B-h1]; plane = [64 rp][64 k] f16.
// Half h (A and B alike) = rows with bit5==h; rp = (r>>5)*32 + (r&31).
// Swizzle involution: byte ^= ((byte>>7)&7)<<4 (slot = lh ^ (rp&7), 2-way free).

template<int HALF>
__device__ __forceinline__ void stage_half(const _Float16* __restrict__ G, int row0,
                                           int col0, _Float16* plane, int tid) {
  #pragma unroll
  for (int is = 0; is < 2; ++is) {
    int lin = is * 4096 + tid * 16;                 // byte offset in plane (8KB)
    int swz = lin ^ (((lin >> 7) & 7) << 4);        // inverse-swizzled source
    int rp = swz >> 7;                              // plane row (0..63)
    int kb = swz & 127;                             // swizzled k-byte
    int row = (rp >> 5) * 64 + HALF * 32 + (rp & 31);
    gload_lds16(G + (size_t)(row0 + row) * 1024 + col0 + (kb >> 1),
                (char*)plane + lin);
  }
}

__device__ __forceinline__ half8 frag_read(const _Float16* plane, int rp, int kk, int lh) {
  int byte = rp * 128 + kk * 64 + lh * 16;
  byte ^= ((byte >> 7) & 7) << 4;
  return *(const half8*)((const char*)plane + byte);
}

template<int MH, int NH>
__device__ __forceinline__ void qreads(const _Float16* sm, int buf,
                                       half8 (&bA)[4], half8 (&bB)[2][4],
                                       int wr, int wc, int lr, int lh) {
  if constexpr (NH == 0) {
    const _Float16* Ap = sm + buf * 16384 + MH * 4096;
    #pragma unroll
    for (int m = 0; m < 2; ++m)
      #pragma unroll
      for (int kk = 0; kk < 2; ++kk)
        bA[m * 2 + kk] = frag_read(Ap, wr * 32 + m * 16 + lr, kk, lh);
  }
  if constexpr (MH == 0) {
    const _Float16* Bp = sm + buf * 16384 + 8192 + NH * 4096;
    #pragma unroll
    for (int n = 0; n < 2; ++n)
      #pragma unroll
      for (int kk = 0; kk < 2; ++kk)
        bB[NH][n * 2 + kk] = frag_read(Bp, wc * 32 + n * 16 + lr, kk, lh);
  }
}

template<int MH, int NH, bool VM4>
__device__ __forceinline__ void qmfma(half8 (&bA)[4], half8 (&bB)[2][4],
                                      floatx4 (&acc)[4][4]) {
  if constexpr (VM4) {
    asm volatile("s_waitcnt vmcnt(4)" ::: "memory");
  }
  __builtin_amdgcn_s_barrier();
  __builtin_amdgcn_s_setprio(1);
  #pragma unroll
  for (int m = 0; m < 2; ++m)
    #pragma unroll
    for (int n = 0; n < 2; ++n)
      #pragma unroll
      for (int kk = 0; kk < 2; ++kk)
        acc[MH * 2 + m][NH * 2 + n] = __builtin_amdgcn_mfma_f32_16x16x32_f16(
            bA[m * 2 + kk], bB[NH][n * 2 + kk], acc[MH * 2 + m][NH * 2 + n], 0, 0, 0);
  __builtin_amdgcn_s_setprio(0);
  __builtin_amdgcn_s_barrier();
}

template<int TBUF>
__device__ __forceinline__ void do_tile(int t, const _Float16* __restrict__ Ab,
                                        const _Float16* __restrict__ Bb,
                                        int i0, int j0, _Float16* sm, int tid,
                                        half8 (&bA)[4], half8 (&bB)[2][4],
                                        floatx4 (&acc)[4][4],
                                        int wr, int wc, int lr, int lh) {
  _Float16* self  = sm + TBUF * 16384;
  _Float16* other = sm + (TBUF ^ 1) * 16384;
  const int c1 = ((t + 1 < 16) ? (t + 1) : 15) * 64;   // clamp: keep vmcnt counts uniform
  const int c2 = ((t + 2 < 16) ? (t + 2) : 15) * 64;
  // ph0 (MH0,NH0)
  qreads<0, 0>(sm, TBUF, bA, bB, wr, wc, lr, lh);
  stage_half<1>(Bb, j0, c1, other + 12288, tid);       // t+1 B-h1
  qmfma<0, 0, false>(bA, bB, acc);
  // ph1 (MH0,NH1)
  qreads<0, 1>(sm, TBUF, bA, bB, wr, wc, lr, lh);
  stage_half<1>(Ab, i0, c1, other + 4096, tid);        // t+1 A-h1
  qmfma<0, 1, false>(bA, bB, acc);
  // ph2 (MH1,NH0)
  qreads<1, 0>(sm, TBUF, bA, bB, wr, wc, lr, lh);
  stage_half<0>(Ab, i0, c2, self + 0, tid);            // t+2 A-h0 (self buf; WAR-safe)
  qmfma<1, 0, false>(bA, bB, acc);
  // ph3 (MH1,NH1) — no reads
  stage_half<0>(Bb, j0, c2, self + 8192, tid);         // t+2 B-h0 (self)
  qmfma<1, 1, true>(bA, bB, acc);                      // single vmcnt(4) per K-tile
}

// MODE 0: Q-proj: phi + z-fold (aux = ksum, read) -> f16 qp
// MODE 1: fused K|V proj, one head per tile: aux = ksum partials (write),
//         aux2 = kv partials (write).  No C output.
// MODE 2: f32 C*outScale, BT indexed per-batch
template<int MODE, bool PHI>
__global__ __launch_bounds__(256, 2)
void k_gemm(const _Float16* __restrict__ A, const _Float16* __restrict__ BT,
            void* __restrict__ Cptr, float* __restrict__ aux, float* __restrict__ aux2,
            float outScale) {
  __shared__ __align__(16) _Float16 smem[32768];   // 64 KiB
  const int tid  = threadIdx.x;
  const int lane = tid & 63;
  const int wid  = tid >> 6;
  const int wr = wid >> 1, wc = wid & 1;
  const int lr = lane & 15, lh = lane >> 4;

  // XCD-chunked block swizzle (bijective: nblocks % 8 == 0)
  constexpr int NT = (MODE == 1) ? 16 : 8;                   // N-tiles
  constexpr int CH = (MODE == 1) ? 512 : 256;                // tiles per XCD chunk
  const int tile = (blockIdx.x & 7) * CH + (blockIdx.x >> 3);
  const int tm = tile / NT, tn = tile % NT;
  const int i0 = tm * 128, j0 = tn * 128;

  const _Float16* Ab = A;
  const _Float16* Bb = (MODE == 2) ? BT + ((size_t)(i0 >> 13)) * ((size_t)NN * KK) : BT;

  floatx4 acc[4][4];
  #pragma unroll
  for (int m = 0; m < 4; ++m)
    #pragma unroll
    for (int n = 0; n < 4; ++n)
      #pragma unroll
      for (int r = 0; r < 4; ++r) acc[m][n][r] = 0.f;

  _Float16* sm = (_Float16*)smem;
  half8 bA[4];
  half8 bB[2][4];

  // prologue: t0's 4 planes + t1's A-h0,B-h0 (6 stages = 12 loads); vmcnt(4)
  stage_half<0>(Ab, i0, 0,  sm + 0,            tid);
  stage_half<0>(Bb, j0, 0,  sm + 8192,         tid);
  stage_half<1>(Bb, j0, 0,  sm + 12288,        tid);
  stage_half<1>(Ab, i0, 0,  sm + 4096,         tid);
  stage_half<0>(Ab, i0, 64, sm + 16384,        tid);
  stage_half<0>(Bb, j0, 64, sm + 16384 + 8192, tid);
  asm volatile("s_waitcnt vmcnt(4)" ::: "memory");
  __builtin_amdgcn_s_barrier();

  #pragma unroll 1
  for (int tt = 0; tt < 8; ++tt) {
    do_tile<0>(2 * tt,     Ab, Bb, i0, j0, sm, tid, bA, bB, acc, wr, wc, lr, lh);
    do_tile<1>(2 * tt + 1, Ab, Bb, i0, j0, sm, tid, bA, bB, acc, wr, wc, lr, lh);
  }

  asm volatile("s_waitcnt vmcnt(0)" ::: "memory");
  __builtin_amdgcn_s_barrier();

  if constexpr (MODE == 0) {
    // z-fold epilogue: p = phi(acc); dot = sum_d p*ksum over this head's 64 cols
    // (head = (j0 + wc*64)/64; cols live entirely in this wave)
    _Float16* C = (_Float16*)Cptr;
    const int bq = i0 >> 13;
    float ks[4];
    #pragma unroll
    for (int n = 0; n < 4; ++n)
      ks[n] = aux[(size_t)bq * 1024 + j0 + wc * 64 + n * 16 + lr];
    #pragma unroll
    for (int m = 0; m < 4; ++m) {
      int row = i0 + wr * 64 + m * 16 + lh * 4;
      #pragma unroll
      for (int r = 0; r < 4; ++r) {
        float p[4];
        float dot = 0.f;
        #pragma unroll
        for (int n = 0; n < 4; ++n) {
          p[n] = phi_act(acc[m][n][r]);
          dot = fmaf(p[n], ks[n], dot);
        }
        dot += __shfl_xor(dot, 1);
        dot += __shfl_xor(dot, 2);
        dot += __shfl_xor(dot, 4);
        dot += __shfl_xor(dot, 8);
        float zf = ZSCALE / (dot + 1e-6f);
        #pragma unroll
        for (int n = 0; n < 4; ++n)
          C[(size_t)(row + r) * NN + j0 + wc * 64 + n * 16 + lr] = (_Float16)(p[n] * zf);
      }
    }
  } else if constexpr (MODE == 2) {
    float* C = (float*)Cptr;
    #pragma unroll
    for (int m = 0; m < 4; ++m) {
      int row = i0 + wr * 64 + m * 16 + lh * 4;
      #pragma unroll
      for (int n = 0; n < 4; ++n) {
        int col = j0 + wc * 64 + n * 16 + lr;
        #pragma unroll
        for (int r = 0; r < 4; ++r)
          C[(size_t)(row + r) * NN + col] = acc[m][n][r] * outScale;
      }
    }
  } else {
    // fused K|V epilogue: tile = one head (tn): cols [K | V].
    // 1) LDS transpose (128 n x 128 l f16 = 32KB, swizzled) + phi/ksum on K;
    // 2) in-block kv partials: kv[d][e] += phiK[l,d]*V[l,e] via MFMA (K=128).
    const int b  = i0 >> 13;
    const int l0 = i0 & 8191;
    const int isK = (wc == 0);                 // wave-uniform
    char* smb = (char*)smem;
    float s[4] = {0.f, 0.f, 0.f, 0.f};
    #pragma unroll
    for (int m = 0; m < 4; ++m) {
      int l0l = wr * 64 + m * 16 + lh * 4;
      #pragma unroll
      for (int n = 0; n < 4; ++n) {
        int n_loc = wc * 64 + n * 16 + lr;
        int byte = (n_loc * 256 + l0l * 2) ^ ((n_loc & 7) << 4);
        half4v h;
        #pragma unroll
        for (int r = 0; r < 4; ++r) {
          float v = acc[m][n][r];
          if (isK) { v = phi_act(v); s[n] += v; }
          h[r] = (_Float16)v;
        }
        *(half4v*)(smb + byte) = h;
      }
    }
    if (isK) {
      #pragma unroll
      for (int n = 0; n < 4; ++n) {
        s[n] += __shfl_xor(s[n], 16);
        s[n] += __shfl_xor(s[n], 32);
      }
      if (lh == 0) {
        int ch = (l0 >> 6) + wr;                     // 128 chunks of 64 l-rows per b
        size_t base = ((size_t)b * 128 + ch) * 1024 + (size_t)tn * 64 + lr;
        #pragma unroll
        for (int n = 0; n < 4; ++n) aux[base + n * 16] = s[n];
      }
    }
    __syncthreads();
    // kv partials: wave w -> d-block (w>>1)*32, e-block (w&1)*32; K=128 (4 steps)
    const int db = (wid >> 1) * 32, eb = (wid & 1) * 32;
    floatx4 a2[2][2];
    #pragma unroll
    for (int md = 0; md < 2; ++md)
      #pragma unroll
      for (int ne = 0; ne < 2; ++ne)
        #pragma unroll
        for (int r = 0; r < 4; ++r) a2[md][ne][r] = 0.f;
    #pragma unroll 1
    for (int ks2 = 0; ks2 < 4; ++ks2) {
      half8 af[2], bf[2];
      #pragma unroll
      for (int md = 0; md < 2; ++md) {
        int n_loc = db + md * 16 + lr;               // phiK^T row (d over l)
        int byte = (n_loc * 256 + ks2 * 64 + lh * 16) ^ ((n_loc & 7) << 4);
        af[md] = *(const half8*)(smb + byte);
      }
      #pragma unroll
      for (int ne = 0; ne < 2; ++ne) {
        int n_loc = 64 + eb + ne * 16 + lr;          // V^T row (e over l)
        int byte = (n_loc * 256 + ks2 * 64 + lh * 16) ^ ((n_loc & 7) << 4);
        bf[ne] = *(const half8*)(smb + byte);
      }
      #pragma unroll
      for (int md = 0; md < 2; ++md)
        #pragma unroll
        for (int ne = 0; ne < 2; ++ne)
          a2[md][ne] = __builtin_amdgcn_mfma_f32_16x16x32_f16(af[md], bf[ne], a2[md][ne], 0, 0, 0);
    }
    const int lch = l0 >> 7;                         // 64 chunks of 128 l-rows per b
    float* op = aux2 + (((size_t)b * 16 + tn) * 64 + lch) * 4096;
    #pragma unroll
    for (int md = 0; md < 2; ++md)
      #pragma unroll
      for (int ne = 0; ne < 2; ++ne)
        #pragma unroll
        for (int r = 0; r < 4; ++r)
          op[(db + md * 16 + lh * 4 + r) * 64 + eb + ne * 16 + lr] = a2[md][ne][r];
  }
}

// ---------- reduce ksum partials: ksum[b][col] = sum_128 part[b][ch][col] ----------
__global__ void k_ksum_red(const float* __restrict__ part, float* __restrict__ ksum) {
  int i = blockIdx.x * 256 + threadIdx.x;     // 4096
  int b = i >> 10, col = i & 1023;
  float s = 0.f;
  for (int c = 0; c < 128; ++c) s += part[((size_t)b * 128 + c) * 1024 + col];
  ksum[i] = s;
}

// ---------- reduce kv partials over 64 chunks ----------
__global__ void k_reduce_kv(const float* __restrict__ kvpart, float* __restrict__ kv) {
  int gid = blockIdx.x * 256 + threadIdx.x;   // 262144
  int bh = gid >> 12, i = gid & 4095;
  float s = 0.f;
  for (int c = 0; c < 64; ++c) s += kvpart[((size_t)bh * 64 + c) * 4096 + i];
  kv[gid] = s;
}

// ---------- MT[b][f][h*64+d] = sum_e kv[b,h,d,e] * Wo[h,e,f] ----------
__global__ __launch_bounds__(256)
void k_mker(const float* __restrict__ kv, const _Float16* __restrict__ Wo16,
            _Float16* __restrict__ MT) {
  __shared__ float kvs[4096];
  int bid = blockIdx.x;
  int fc = bid & 3, h = (bid >> 2) & 15, b = bid >> 6;
  const float* kvp = kv + ((size_t)b * 16 + h) * 4096;
  for (int i = threadIdx.x; i < 4096; i += 256) kvs[i] = kvp[i];
  __syncthreads();
  int f = fc * 256 + threadIdx.x;
  float acc[64];
  #pragma unroll
  for (int d = 0; d < 64; ++d) acc[d] = 0.f;
  for (int e = 0; e < 64; ++e) {
    float wv = (float)Wo16[(size_t)(h * 64 + e) * 1024 + f];
    #pragma unroll
    for (int d = 0; d < 64; ++d) acc[d] = fmaf(kvs[d * 64 + e], wv, acc[d]);
  }
  _Float16* op = MT + ((size_t)b * 1024 + f) * 1024 + h * 64;
  #pragma unroll
  for (int g = 0; g < 8; ++g) {
    half8 o;
    #pragma unroll
    for (int j = 0; j < 8; ++j) o[j] = (_Float16)acc[g * 8 + j];
    *(half8*)&op[g * 8] = o;
  }
}

extern "C" void kernel_launch(void* const* d_in, const int* in_sizes, int n_in,
                              void* d_out, int out_size, void* d_ws, size_t ws_size,
                              hipStream_t stream) {
  (void)in_sizes; (void)n_in; (void)out_size; (void)ws_size;
  const float* xq  = (const float*)d_in[0];
  const float* xkv = (const float*)d_in[1];
  const float* Wq  = (const float*)d_in[2];
  const float* Wk  = (const float*)d_in[3];
  const float* Wv  = (const float*)d_in[4];
  const float* Wo  = (const float*)d_in[5];

  char* ws = (char*)d_ws;
  _Float16* qp16   = (_Float16*)(ws + 0);          // 64MB [32768][1024]
  float*    kvpart = (float*)(ws + 67108864);      // 64MB [4][16][64][4096]
  float*    ksum_part = (float*)(ws + 134217728);  // 2MB  [4][128][1024]
  float*    ksum   = (float*)(ws + 136314880);     // 16KB [4][1024]
  float*    kv     = (float*)(ws + 136331264);     // 1MB  [4][16][64][64]
  _Float16* WqT    = (_Float16*)(ws + 137379840);  // 2MB
  _Float16* WKV    = (_Float16*)(ws + 139476992);  // 4MB  [2048][1024] head-interleaved
  _Float16* Wo16   = (_Float16*)(ws + 143671296);  // 2MB
  _Float16* MT     = (_Float16*)(ws + 145768448);  // 8MB  [4][1024][1024]

  _Float16* Xq16  = (_Float16*)d_out;
  _Float16* Xkv16 = Xq16 + 33554432;

  // input + weight conversion
  k_cvt2<<<4096, 256, 0, stream>>>(xq, xkv, Xq16, Xkv16, 8388608);
  k_cvt<<<512,  256, 0, stream>>>(Wo, Wo16, 262144);
  k_cvt_t<<<3072, 256, 0, stream>>>(Wq, Wk, Wv, WqT, WKV);

  // fused K|V projection -> ksum partials + kv partials
  k_gemm<1, false><<<4096, 256, 0, stream>>>(Xkv16, WKV, nullptr, ksum_part, kvpart, 1.0f);
  k_ksum_red<<<16, 256, 0, stream>>>(ksum_part, ksum);
  k_reduce_kv<<<1024, 256, 0, stream>>>(kvpart, kv);
  k_mker<<<256, 256, 0, stream>>>(kv, Wo16, MT);

  // Q projection with fused phi + z scaling (reads ksum)
  k_gemm<0, true><<<2048, 256, 0, stream>>>(Xq16, WqT, qp16, ksum, nullptr, 1.0f);

  // final GEMM -> d_out (f32), undo 2^16 scale
  k_gemm<2, false><<<2048, 256, 0, stream>>>(qp16, MT, d_out, nullptr, nullptr, 1.0f / ZSCALE);
}

// Round 16
// 429.137 us; speedup vs baseline: 1.1432x; 1.1432x over previous
//
#include <hip/hip_runtime.h>
#include <hip/hip_fp16.h>
#include <math.h>

typedef _Float16 half8  __attribute__((ext_vector_type(8)));
typedef _Float16 half4v __attribute__((ext_vector_type(4)));
typedef float    floatx4 __attribute__((ext_vector_type(4)));

#define NB   4
#define LL   8192
#define FF   1024
#define HH   16
#define DD   64
#define MTOT 32768
#define KK   1024
#define NN   1024
#define ZSCALE 65536.0f

__device__ __forceinline__ void gload_lds16(const void* g, void* l) {
  __builtin_amdgcn_global_load_lds(
      (const __attribute__((address_space(1))) void*)g,
      (__attribute__((address_space(3))) void*)l, 16, 0, 0);
}

__device__ __forceinline__ float phi_act(float x) {
  return x > 0.f ? x + 1.f : __expf(x);
}

// ---------- fused elementwise f32 -> f16 for two arrays ----------
__global__ void k_cvt2(const float* __restrict__ a, const float* __restrict__ b,
                       _Float16* __restrict__ da, _Float16* __restrict__ db, int n4each) {
  int stride = gridDim.x * blockDim.x;
  for (int i = blockIdx.x * blockDim.x + threadIdx.x; i < 2 * n4each; i += stride) {
    const float* s; _Float16* d; int j;
    if (i < n4each) { s = a; d = da; j = i; }
    else            { s = b; d = db; j = i - n4each; }
    float4 v = reinterpret_cast<const float4*>(s)[j];
    half4v h;
    h[0] = (_Float16)v.x; h[1] = (_Float16)v.y; h[2] = (_Float16)v.z; h[3] = (_Float16)v.w;
    reinterpret_cast<half4v*>(d)[j] = h;
  }
}

// ---------- elementwise f32 -> f16 ----------
__global__ void k_cvt(const float* __restrict__ src, _Float16* __restrict__ dst, int n4) {
  int stride = gridDim.x * blockDim.x;
  for (int i = blockIdx.x * blockDim.x + threadIdx.x; i < n4; i += stride) {
    float4 v = reinterpret_cast<const float4*>(src)[i];
    half4v h;
    h[0] = (_Float16)v.x; h[1] = (_Float16)v.y; h[2] = (_Float16)v.z; h[3] = (_Float16)v.w;
    reinterpret_cast<half4v*>(dst)[i] = h;
  }
}

// ---------- transpose+convert weights ----------
// Wq -> T0 [1024][1024]; Wk,Wv -> TKV [2048][1024] interleaved per head:
//   head h rows h*128..h*128+63 = WkT(h), rows h*128+64..+127 = WvT(h).
__global__ void k_cvt_t(const float* __restrict__ W0, const float* __restrict__ W1,
                        const float* __restrict__ W2,
                        _Float16* __restrict__ T0, _Float16* __restrict__ TKV) {
  __shared__ float tile[32][33];
  int bid = blockIdx.x;
  int w = bid >> 10, rem = bid & 1023;
  int ti = rem >> 5, tj = rem & 31;
  const float* src = (w == 0) ? W0 : (w == 1) ? W1 : W2;
  int t = threadIdx.x;
  int r = t >> 3, c4 = (t & 7) << 2;
  float4 v = *reinterpret_cast<const float4*>(&src[(size_t)(ti * 32 + r) * FF + tj * 32 + c4]);
  tile[r][c4 + 0] = v.x; tile[r][c4 + 1] = v.y; tile[r][c4 + 2] = v.z; tile[r][c4 + 3] = v.w;
  __syncthreads();
  half4v h;
  h[0] = (_Float16)tile[c4 + 0][r];
  h[1] = (_Float16)tile[c4 + 1][r];
  h[2] = (_Float16)tile[c4 + 2][r];
  h[3] = (_Float16)tile[c4 + 3][r];
  int n = tj * 32 + r;
  _Float16* dst; size_t orow;
  if (w == 0) { dst = T0;  orow = n; }
  else        { dst = TKV; orow = (size_t)(n >> 6) * 128 + (n & 63) + (w == 2 ? 64 : 0); }
  *reinterpret_cast<half4v*>(&dst[orow * FF + ti * 32 + c4]) = h;
}

// ============ 256x256-tile quadrant-schedule GEMM (BK=64, 8 waves 2x4) ============
// Best measured config (r12/r14, 431 µs): MODE 1 computes kv partials in-block
// (no kpT/vT).  r13 addr-hoist and r15 tile-halving both regressed — reverted.

template<int MATB, int HALF>
__device__ __forceinline__ void stage_half(const _Float16* __restrict__ G, int row0,
                                           int col0, _Float16* plane, int tid) {
  #pragma unroll
  for (int is = 0; is < 2; ++is) {
    int lin = is * 8192 + tid * 16;                 // byte offset in plane
    int swz = lin ^ (((lin >> 7) & 7) << 4);        // inverse-swizzled source
    int rp = swz >> 7;                              // plane row (= lin>>7)
    int kb = swz & 127;                             // swizzled k-byte
    int row;
    if constexpr (MATB) row = (rp >> 5) * 64 + HALF * 32 + (rp & 31);
    else                row = (rp >> 6) * 128 + HALF * 64 + (rp & 63);
    gload_lds16(G + (size_t)(row0 + row) * 1024 + col0 + (kb >> 1),
                (char*)plane + lin);
  }
}

__device__ __forceinline__ half8 frag_read(const _Float16* plane, int rp, int kk, int lh) {
  int byte = rp * 128 + kk * 64 + lh * 16;
  byte ^= ((byte >> 7) & 7) << 4;
  return *(const half8*)((const char*)plane + byte);
}

template<int MH, int NH>
__device__ __forceinline__ void qreads(const _Float16* sm, int buf,
                                       half8 (&bA)[8], half8 (&bB)[2][4],
                                       int wr, int wc, int lr, int lh) {
  if constexpr (NH == 0) {
    const _Float16* Ap = sm + buf * 32768 + MH * 8192;
    #pragma unroll
    for (int m = 0; m < 4; ++m)
      #pragma unroll
      for (int kk = 0; kk < 2; ++kk)
        bA[m * 2 + kk] = frag_read(Ap, wr * 64 + m * 16 + lr, kk, lh);
  }
  if constexpr (MH == 0) {
    const _Float16* Bp = sm + buf * 32768 + 16384 + NH * 8192;
    #pragma unroll
    for (int n = 0; n < 2; ++n)
      #pragma unroll
      for (int kk = 0; kk < 2; ++kk)
        bB[NH][n * 2 + kk] = frag_read(Bp, wc * 32 + n * 16 + lr, kk, lh);
  }
}

template<int MH, int NH, bool VM4>
__device__ __forceinline__ void qmfma(half8 (&bA)[8], half8 (&bB)[2][4],
                                      floatx4 (&acc)[8][4]) {
  if constexpr (VM4) {
    asm volatile("s_waitcnt vmcnt(4)" ::: "memory");
  }
  __builtin_amdgcn_s_barrier();
  __builtin_amdgcn_s_setprio(1);
  #pragma unroll
  for (int m = 0; m < 4; ++m)
    #pragma unroll
    for (int n = 0; n < 2; ++n)
      #pragma unroll
      for (int kk = 0; kk < 2; ++kk)
        acc[MH * 4 + m][NH * 2 + n] = __builtin_amdgcn_mfma_f32_16x16x32_f16(
            bA[m * 2 + kk], bB[NH][n * 2 + kk], acc[MH * 4 + m][NH * 2 + n], 0, 0, 0);
  __builtin_amdgcn_s_setprio(0);
  __builtin_amdgcn_s_barrier();
}

template<int TBUF>
__device__ __forceinline__ void do_tile(int t, const _Float16* __restrict__ Ab,
                                        const _Float16* __restrict__ Bb,
                                        int i0, int j0, _Float16* sm, int tid,
                                        half8 (&bA)[8], half8 (&bB)[2][4],
                                        floatx4 (&acc)[8][4],
                                        int wr, int wc, int lr, int lh) {
  _Float16* self  = sm + TBUF * 32768;
  _Float16* other = sm + (TBUF ^ 1) * 32768;
  const int c1 = ((t + 1 < 16) ? (t + 1) : 15) * 64;   // clamp: keep vmcnt counts uniform
  const int c2 = ((t + 2 < 16) ? (t + 2) : 15) * 64;
  // ph0 (MH0,NH0)
  qreads<0, 0>(sm, TBUF, bA, bB, wr, wc, lr, lh);
  stage_half<1, 1>(Bb, j0, c1, other + 24576, tid);    // t+1 B-h1
  qmfma<0, 0, false>(bA, bB, acc);
  // ph1 (MH0,NH1)
  qreads<0, 1>(sm, TBUF, bA, bB, wr, wc, lr, lh);
  stage_half<0, 1>(Ab, i0, c1, other + 8192, tid);     // t+1 A-h1
  qmfma<0, 1, false>(bA, bB, acc);
  // ph2 (MH1,NH0)
  qreads<1, 0>(sm, TBUF, bA, bB, wr, wc, lr, lh);
  stage_half<0, 0>(Ab, i0, c2, self + 0, tid);         // t+2 A-h0 (self buf; WAR-safe)
  qmfma<1, 0, false>(bA, bB, acc);
  // ph3 (MH1,NH1) — no reads
  stage_half<1, 0>(Bb, j0, c2, self + 16384, tid);     // t+2 B-h0 (self)
  qmfma<1, 1, true>(bA, bB, acc);                      // single vmcnt(4) per K-tile
}

// MODE 0: Q-proj: phi + z-fold (aux = ksum, read) -> f16 qp
// MODE 1: fused K|V proj (interleaved heads): aux = ksum partials (write),
//         aux2 = kv partials (write).  No C output.
// MODE 2: f32 C*outScale, BT indexed per-batch
template<int MODE, bool PHI>
__global__ __launch_bounds__(512, 2)
void k_gemm(const _Float16* __restrict__ A, const _Float16* __restrict__ BT,
            void* __restrict__ Cptr, float* __restrict__ aux, float* __restrict__ aux2,
            float outScale) {
  __shared__ __align__(16) _Float16 smem[65536];   // 128 KiB
  const int tid  = threadIdx.x;
  const int lane = tid & 63;
  const int wid  = tid >> 6;
  const int wr = wid >> 2, wc = wid & 3;
  const int lr = lane & 15, lh = lane >> 4;

  // XCD-chunked block swizzle (bijective: ntiles % 8 == 0)
  constexpr int NT = (MODE == 1) ? 8 : 4;                    // N-tiles
  constexpr int CH = (MODE == 1) ? 128 : 64;                 // tiles per XCD chunk
  const int tile = (blockIdx.x & 7) * CH + (blockIdx.x >> 3);
  const int tm = tile / NT, tn = tile % NT;
  const int i0 = tm * 256, j0 = tn * 256;

  const _Float16* Ab = A;
  const _Float16* Bb = (MODE == 2) ? BT + ((size_t)(i0 >> 13)) * ((size_t)NN * KK) : BT;

  floatx4 acc[8][4];
  #pragma unroll
  for (int m = 0; m < 8; ++m)
    #pragma unroll
    for (int n = 0; n < 4; ++n)
      #pragma unroll
      for (int r = 0; r < 4; ++r) acc[m][n][r] = 0.f;

  _Float16* sm = (_Float16*)smem;
  half8 bA[8];
  half8 bB[2][4];

  // prologue: t0's 4 planes + t1's A-h0,B-h0 (6 stages = 12 loads); vmcnt(4)
  stage_half<0, 0>(Ab, i0, 0,  sm + 0,             tid);
  stage_half<1, 0>(Bb, j0, 0,  sm + 16384,         tid);
  stage_half<1, 1>(Bb, j0, 0,  sm + 24576,         tid);
  stage_half<0, 1>(Ab, i0, 0,  sm + 8192,          tid);
  stage_half<0, 0>(Ab, i0, 64, sm + 32768 + 0,     tid);
  stage_half<1, 0>(Bb, j0, 64, sm + 32768 + 16384, tid);
  asm volatile("s_waitcnt vmcnt(4)" ::: "memory");
  __builtin_amdgcn_s_barrier();

  #pragma unroll 1
  for (int tt = 0; tt < 8; ++tt) {
    do_tile<0>(2 * tt,     Ab, Bb, i0, j0, sm, tid, bA, bB, acc, wr, wc, lr, lh);
    do_tile<1>(2 * tt + 1, Ab, Bb, i0, j0, sm, tid, bA, bB, acc, wr, wc, lr, lh);
  }

  asm volatile("s_waitcnt vmcnt(0)" ::: "memory");
  __builtin_amdgcn_s_barrier();

  if constexpr (MODE == 0) {
    // z-fold epilogue: p = phi(acc); dot = sum_d p*ksum over this head's 64 cols
    _Float16* C = (_Float16*)Cptr;
    const int bq = i0 >> 13;
    float ks[4];
    #pragma unroll
    for (int n = 0; n < 4; ++n)
      ks[n] = aux[(size_t)bq * 1024 + j0 + wc * 64 + n * 16 + lr];
    #pragma unroll
    for (int m = 0; m < 8; ++m) {
      int row = i0 + wr * 128 + m * 16 + lh * 4;
      #pragma unroll
      for (int r = 0; r < 4; ++r) {
        float p[4];
        float dot = 0.f;
        #pragma unroll
        for (int n = 0; n < 4; ++n) {
          p[n] = phi_act(acc[m][n][r]);
          dot = fmaf(p[n], ks[n], dot);
        }
        dot += __shfl_xor(dot, 1);
        dot += __shfl_xor(dot, 2);
        dot += __shfl_xor(dot, 4);
        dot += __shfl_xor(dot, 8);
        float zf = ZSCALE / (dot + 1e-6f);
        #pragma unroll
        for (int n = 0; n < 4; ++n)
          C[(size_t)(row + r) * NN + j0 + wc * 64 + n * 16 + lr] = (_Float16)(p[n] * zf);
      }
    }
  } else if constexpr (MODE == 2) {
    float* C = (float*)Cptr;
    #pragma unroll
    for (int m = 0; m < 8; ++m) {
      int row = i0 + wr * 128 + m * 16 + lh * 4;
      #pragma unroll
      for (int n = 0; n < 4; ++n) {
        int col = j0 + wc * 64 + n * 16 + lr;
        #pragma unroll
        for (int r = 0; r < 4; ++r)
          C[(size_t)(row + r) * NN + col] = acc[m][n][r] * outScale;
      }
    }
  } else {
    // fused K|V epilogue: tile cols = [K(h0)|V(h0)|K(h1)|V(h1)], h0 = 2tn.
    // 1) LDS transpose store (swizzled) with phi on K cols + ksum partials;
    // 2) in-block kv partials: kv[d][e] += phiK[l,d]*V[l,e] via MFMA (K=256).
    const int b  = i0 >> 13;
    const int l0 = i0 & 8191;
    const int isK = !(wc & 1);                 // wave-uniform: wc 0,2 = K cols
    const int hh  = tn * 2 + (wc >> 1);        // this wave's head (global)
    float s[4] = {0.f, 0.f, 0.f, 0.f};
    #pragma unroll
    for (int m = 0; m < 8; ++m) {
      int l0l = wr * 128 + m * 16 + lh * 4;
      #pragma unroll
      for (int n = 0; n < 4; ++n) {
        int n_loc = wc * 64 + n * 16 + lr;
        int byte = (n_loc * 512 + l0l * 2) ^ ((n_loc & 7) << 4);
        half4v h;
        #pragma unroll
        for (int r = 0; r < 4; ++r) {
          float v = acc[m][n][r];
          if (isK) { v = phi_act(v); s[n] += v; }
          h[r] = (_Float16)v;
        }
        *(half4v*)((char*)sm + byte) = h;
      }
    }
    if (isK) {
      #pragma unroll
      for (int n = 0; n < 4; ++n) {
        s[n] += __shfl_xor(s[n], 16);
        s[n] += __shfl_xor(s[n], 32);
      }
      if (lh == 0) {
        int ch = (l0 >> 7) + wr;                     // 64 chunks of 128 l-rows per b
        size_t base = ((size_t)b * 64 + ch) * 1024 + (size_t)hh * 64 + lr;
        #pragma unroll
        for (int n = 0; n < 4; ++n) aux[base + n * 16] = s[n];
      }
    }
    __syncthreads();
    // kv partials: wave w -> head (w>>2), d-block ((w>>1)&1)*32, e-block (w&1)*32
    const int khd = wid >> 2;
    const int db = ((wid >> 1) & 1) * 32, eb = (wid & 1) * 32;
    const int hb = khd * 128;                        // tile-local head base (n_loc)
    floatx4 a2[2][2];
    #pragma unroll
    for (int md = 0; md < 2; ++md)
      #pragma unroll
      for (int ne = 0; ne < 2; ++ne)
        #pragma unroll
        for (int r = 0; r < 4; ++r) a2[md][ne][r] = 0.f;
    #pragma unroll 1
    for (int ks2 = 0; ks2 < 8; ++ks2) {
      half8 af[2], bf[2];
      #pragma unroll
      for (int md = 0; md < 2; ++md) {
        int n_loc = hb + db + md * 16 + lr;          // phiK^T row (d over l)
        int byte = (n_loc * 512 + ks2 * 64 + lh * 16) ^ ((n_loc & 7) << 4);
        af[md] = *(const half8*)((const char*)sm + byte);
      }
      #pragma unroll
      for (int ne = 0; ne < 2; ++ne) {
        int n_loc = hb + 64 + eb + ne * 16 + lr;     // V^T row (e over l)
        int byte = (n_loc * 512 + ks2 * 64 + lh * 16) ^ ((n_loc & 7) << 4);
        bf[ne] = *(const half8*)((const char*)sm + byte);
      }
      #pragma unroll
      for (int md = 0; md < 2; ++md)
        #pragma unroll
        for (int ne = 0; ne < 2; ++ne)
          a2[md][ne] = __builtin_amdgcn_mfma_f32_16x16x32_f16(af[md], bf[ne], a2[md][ne], 0, 0, 0);
    }
    const int lch = l0 >> 8;                         // 32 chunks of 256 l-rows per b
    float* op = aux2 + ((((size_t)b * 16 + tn * 2 + khd) * 32) + lch) * 4096;
    #pragma unroll
    for (int md = 0; md < 2; ++md)
      #pragma unroll
      for (int ne = 0; ne < 2; ++ne)
        #pragma unroll
        for (int r = 0; r < 4; ++r)
          op[(db + md * 16 + lh * 4 + r) * 64 + eb + ne * 16 + lr] = a2[md][ne][r];
  }
}

// ---------- reduce ksum partials: ksum[b][col] = sum_64 part[b][ch][col] ----------
__global__ void k_ksum_red(const float* __restrict__ part, float* __restrict__ ksum) {
  int i = blockIdx.x * 256 + threadIdx.x;     // 4096
  int b = i >> 10, col = i & 1023;
  float s = 0.f;
  for (int c = 0; c < 64; ++c) s += part[((size_t)b * 64 + c) * 1024 + col];
  ksum[i] = s;
}

// ---------- reduce kv partials over 32 chunks ----------
__global__ void k_reduce_kv(const float* __restrict__ kvpart, float* __restrict__ kv) {
  int gid = blockIdx.x * 256 + threadIdx.x;   // 262144
  int bh = gid >> 12, i = gid & 4095;
  float s = 0.f;
  for (int c = 0; c < 32; ++c) s += kvpart[((size_t)bh * 32 + c) * 4096 + i];
  kv[gid] = s;
}

// ---------- MT[b][f][h*64+d] = sum_e kv[b,h,d,e] * Wo[h,e,f] ----------
__global__ __launch_bounds__(256)
void k_mker(const float* __restrict__ kv, const _Float16* __restrict__ Wo16,
            _Float16* __restrict__ MT) {
  __shared__ float kvs[4096];
  int bid = blockIdx.x;
  int fc = bid & 3, h = (bid >> 2) & 15, b = bid >> 6;
  const float* kvp = kv + ((size_t)b * 16 + h) * 4096;
  for (int i = threadIdx.x; i < 4096; i += 256) kvs[i] = kvp[i];
  __syncthreads();
  int f = fc * 256 + threadIdx.x;
  float acc[64];
  #pragma unroll
  for (int d = 0; d < 64; ++d) acc[d] = 0.f;
  for (int e = 0; e < 64; ++e) {
    float wv = (float)Wo16[(size_t)(h * 64 + e) * 1024 + f];
    #pragma unroll
    for (int d = 0; d < 64; ++d) acc[d] = fmaf(kvs[d * 64 + e], wv, acc[d]);
  }
  _Float16* op = MT + ((size_t)b * 1024 + f) * 1024 + h * 64;
  #pragma unroll
  for (int g = 0; g < 8; ++g) {
    half8 o;
    #pragma unroll
    for (int j = 0; j < 8; ++j) o[j] = (_Float16)acc[g * 8 + j];
    *(half8*)&op[g * 8] = o;
  }
}

extern "C" void kernel_launch(void* const* d_in, const int* in_sizes, int n_in,
                              void* d_out, int out_size, void* d_ws, size_t ws_size,
                              hipStream_t stream) {
  (void)in_sizes; (void)n_in; (void)out_size; (void)ws_size;
  const float* xq  = (const float*)d_in[0];
  const float* xkv = (const float*)d_in[1];
  const float* Wq  = (const float*)d_in[2];
  const float* Wk  = (const float*)d_in[3];
  const float* Wv  = (const float*)d_in[4];
  const float* Wo  = (const float*)d_in[5];

  char* ws = (char*)d_ws;
  _Float16* qp16   = (_Float16*)(ws + 0);          // 64MB [32768][1024]
  float*    kvpart = (float*)(ws + 67108864);      // 32MB [4][16][32][4096]
  float*    ksum_part = (float*)(ws + 100663296);  // 1MB  [4][64][1024]
  float*    ksum   = (float*)(ws + 101711872);     // 16KB [4][1024]
  float*    kv     = (float*)(ws + 101728256);     // 1MB  [4][16][64][64]
  _Float16* WqT    = (_Float16*)(ws + 102776832);  // 2MB
  _Float16* WKV    = (_Float16*)(ws + 104873984);  // 4MB  [2048][1024] head-interleaved
  _Float16* Wo16   = (_Float16*)(ws + 109068288);  // 2MB
  _Float16* MT     = (_Float16*)(ws + 111165440);  // 8MB  [4][1024][1024]

  _Float16* Xq16  = (_Float16*)d_out;
  _Float16* Xkv16 = Xq16 + 33554432;

  // input + weight conversion
  k_cvt2<<<4096, 256, 0, stream>>>(xq, xkv, Xq16, Xkv16, 8388608);
  k_cvt<<<512,  256, 0, stream>>>(Wo, Wo16, 262144);
  k_cvt_t<<<3072, 256, 0, stream>>>(Wq, Wk, Wv, WqT, WKV);

  // fused K|V projection -> ksum partials + kv partials (no kpT/vT materialization)
  k_gemm<1, false><<<1024, 512, 0, stream>>>(Xkv16, WKV, nullptr, ksum_part, kvpart, 1.0f);
  k_ksum_red<<<16, 256, 0, stream>>>(ksum_part, ksum);
  k_reduce_kv<<<1024, 256, 0, stream>>>(kvpart, kv);
  k_mker<<<256, 256, 0, stream>>>(kv, Wo16, MT);

  // Q projection with fused phi + z scaling (reads ksum)
  k_gemm<0, true><<<512, 512, 0, stream>>>(Xq16, WqT, qp16, ksum, nullptr, 1.0f);

  // final GEMM -> d_out (f32), undo 2^16 scale
  k_gemm<2, false><<<512, 512, 0, stream>>>(qp16, MT, d_out, nullptr, nullptr, 1.0f / ZSCALE);
}